// Round 1
// baseline (1715.016 us; speedup 1.0000x reference)
//
#include <hip/hip_runtime.h>
#include <stdint.h>

typedef __bf16 bf16;
typedef __bf16 bf16x4 __attribute__((ext_vector_type(4)));
typedef __bf16 bf16x8 __attribute__((ext_vector_type(8)));
typedef float f32x4 __attribute__((ext_vector_type(4)));

#define GLD_LDS16(g, l)                                                        \
  __builtin_amdgcn_global_load_lds(                                            \
      (const __attribute__((address_space(1))) void*)(g),                      \
      (__attribute__((address_space(3))) void*)(l), 16, 0, 0)

// ---------------------------------------------------------------- init: zero ssq accumulators
__global__ void k_init(float* s) {
  if (threadIdx.x < 3) s[threadIdx.x] = 0.0f;
}

// ---------------------------------------------------------------- cast x fp32 -> bf16, fused ||x||^2
__global__ void k_cast_ssq(const float* __restrict__ x, bf16* __restrict__ xb,
                           float* __restrict__ ssq, int n4) {
  int tid = blockIdx.x * blockDim.x + threadIdx.x;
  int stride = gridDim.x * blockDim.x;
  const float4* x4 = (const float4*)x;
  bf16x4* xb4 = (bf16x4*)xb;
  float acc = 0.f;
  for (int i = tid; i < n4; i += stride) {
    float4 v = x4[i];
    acc += v.x * v.x + v.y * v.y + v.z * v.z + v.w * v.w;
    bf16x4 b;
    b.x = (bf16)v.x; b.y = (bf16)v.y; b.z = (bf16)v.z; b.w = (bf16)v.w;
    xb4[i] = b;
  }
#pragma unroll
  for (int off = 32; off; off >>= 1) acc += __shfl_down(acc, off);
  __shared__ float red[4];
  if ((threadIdx.x & 63) == 0) red[threadIdx.x >> 6] = acc;
  __syncthreads();
  if (threadIdx.x == 0) atomicAdd(ssq, red[0] + red[1] + red[2] + red[3]);
}

// ---------------------------------------------------------------- build Wt (bf16, [out=4096][in=4096] row-major)
// W[i,j] = sum_{r1,r2} c0[0,i0,j0,r1] c1[r1,i1,j1,r2] c2[r2,i2,j2,0]
// i = i0*256+i1*16+i2, j = j0*256+j1*16+j2 ; Wt[j,i] = W[i,j]
__global__ void k_buildW(const float* __restrict__ c0, const float* __restrict__ c1,
                         const float* __restrict__ c2, bf16* __restrict__ Wt) {
  int t = blockIdx.x * 256 + threadIdx.x;  // 4096 * 16 * 16 threads
  int j = t >> 8;
  int i0 = (t >> 4) & 15;
  int i1 = t & 15;
  int j0 = j >> 8, j1 = (j >> 4) & 15, j2 = j & 15;
  float t0[8];
#pragma unroll
  for (int r1 = 0; r1 < 8; ++r1) t0[r1] = c0[(i0 * 16 + j0) * 8 + r1];
  float a[8];
#pragma unroll
  for (int r2 = 0; r2 < 8; ++r2) {
    float s = 0.f;
#pragma unroll
    for (int r1 = 0; r1 < 8; ++r1) s += t0[r1] * c1[((r1 * 16 + i1) * 16 + j1) * 8 + r2];
    a[r2] = s;
  }
  union { bf16 h[16]; bf16x8 v[2]; } u;
#pragma unroll
  for (int i2 = 0; i2 < 16; ++i2) {
    float s = 0.f;
#pragma unroll
    for (int r2 = 0; r2 < 8; ++r2) s += a[r2] * c2[(r2 * 16 + i2) * 16 + j2];
    u.h[i2] = (bf16)s;
  }
  bf16* dst = Wt + (size_t)j * 4096 + i0 * 256 + i1 * 16;
  ((bf16x8*)dst)[0] = u.v[0];
  ((bf16x8*)dst)[1] = u.v[1];
}

// ---------------------------------------------------------------- BT-form GEMM: C[m,n] = sum_k A[m,k]*Bt[n,k]
// 128x128 tile, BK=32, 256 thr = 4 waves (2x2 of 64x64), mfma_f32_16x16x32_bf16 4x4/wave.
// MODE 0: mv    -> f32_out[idx]=acc+bias ; bf_out=bf16(that+gate) ; ssq_out += xl^2
// MODE 1: G     -> bf_out = bf16(acc)
// MODE 2: iter  -> xl = xl_prev - acc + mbias_in + gate ; bf_out ; ssq_out
// MODE 3: final -> f32_out = xl_prev - acc + mbias_in + gate   (mbias_in aliases f32_out)
template <int MODE>
__global__ __launch_bounds__(256) void k_gemm(
    const bf16* __restrict__ A, const bf16* __restrict__ Bt, int M, int N, int K,
    const float* __restrict__ bias, const bf16* __restrict__ xl_prev,
    const float* mbias_in, float* f32_out, bf16* __restrict__ bf_out,
    const float* __restrict__ ssq_in, float* __restrict__ ssq_out) {
  __shared__ char smem[16384];  // As[128][32] bf16 | Bs[128][32] bf16
  __shared__ float red[4];
  bf16* As = (bf16*)smem;
  bf16* Bs = (bf16*)(smem + 8192);

  const int t = threadIdx.x;
  const int w = t >> 6, lane = t & 63;
  const int q = lane >> 4, lr = lane & 15;
  const int wm = w & 1, wn = w >> 1;
  const int bx = blockIdx.x, by = blockIdx.y;

  f32x4 acc[4][4];
#pragma unroll
  for (int i = 0; i < 4; ++i)
#pragma unroll
    for (int j = 0; j < 4; ++j) acc[i][j] = (f32x4){0.f, 0.f, 0.f, 0.f};

  // staging: thread t loads 16B chunks t and t+256 of each 128x32 tile (row-major, 64B rows)
  const int rowA = t >> 2;
  const int colc = (t & 3) * 8;
  const bf16* pA = A + (size_t)(by * 128 + rowA) * K + colc;
  const bf16* pA2 = pA + (size_t)64 * K;
  const bf16* pB = Bt + (size_t)(bx * 128 + rowA) * K + colc;
  const bf16* pB2 = pB + (size_t)64 * K;
  char* ldsA = smem + w * 1024;          // wave-uniform bases
  char* ldsA2 = smem + 4096 + w * 1024;
  char* ldsB = smem + 8192 + w * 1024;
  char* ldsB2 = smem + 12288 + w * 1024;

  for (int k0 = 0; k0 < K; k0 += 32) {
    __syncthreads();
    GLD_LDS16(pA, ldsA);
    GLD_LDS16(pA2, ldsA2);
    GLD_LDS16(pB, ldsB);
    GLD_LDS16(pB2, ldsB2);
    pA += 32; pA2 += 32; pB += 32; pB2 += 32;
    __syncthreads();  // drains vmcnt -> LDS valid
    bf16x8 af[4], bfr[4];
#pragma unroll
    for (int mi = 0; mi < 4; ++mi)
      af[mi] = *(const bf16x8*)(As + (wm * 64 + mi * 16 + lr) * 32 + q * 8);
#pragma unroll
    for (int ni = 0; ni < 4; ++ni)
      bfr[ni] = *(const bf16x8*)(Bs + (wn * 64 + ni * 16 + lr) * 32 + q * 8);
#pragma unroll
    for (int mi = 0; mi < 4; ++mi)
#pragma unroll
      for (int ni = 0; ni < 4; ++ni)
        acc[mi][ni] =
            __builtin_amdgcn_mfma_f32_16x16x32_bf16(af[mi], bfr[ni], acc[mi][ni], 0, 0, 0);
  }

  // epilogue. C/D layout: col = lane&15, row = (lane>>4)*4 + reg  [m89-verified]
  float gate = 0.f;
  if constexpr (MODE == 0 || MODE == 2 || MODE == 3)
    gate = (*ssq_in > 1.0f) ? 0.f : -1.f;  // norm > EPSILON(=1) ? 0 : S(=-1)
  float ssql = 0.f;
  const int gm0 = by * 128 + wm * 64 + q * 4;
  const int gn0 = bx * 128 + wn * 64 + lr;
#pragma unroll
  for (int mi = 0; mi < 4; ++mi) {
#pragma unroll
    for (int r = 0; r < 4; ++r) {
      int row = gm0 + mi * 16 + r;
      size_t base = (size_t)row * N + gn0;
#pragma unroll
      for (int ni = 0; ni < 4; ++ni) {
        size_t idx = base + ni * 16;
        float v = acc[mi][ni][r];
        if constexpr (MODE == 0) {
          float mb = v + bias[gn0 + ni * 16];
          f32_out[idx] = mb;              // mbias (fp32, lives in d_out)
          float xl = mb + gate;
          bf_out[idx] = (bf16)xl;
          ssql += xl * xl;
        } else if constexpr (MODE == 1) {
          bf_out[idx] = (bf16)v;
        } else if constexpr (MODE == 2) {
          float xl = (float)xl_prev[idx] - v + mbias_in[idx] + gate;
          bf_out[idx] = (bf16)xl;
          ssql += xl * xl;
        } else {
          float xl = (float)xl_prev[idx] - v + mbias_in[idx] + gate;
          f32_out[idx] = xl;
        }
      }
    }
  }
  if constexpr (MODE == 0 || MODE == 2) {
#pragma unroll
    for (int off = 32; off; off >>= 1) ssql += __shfl_down(ssql, off);
    if (lane == 0) red[w] = ssql;
    __syncthreads();
    if (t == 0) atomicAdd(ssq_out, red[0] + red[1] + red[2] + red[3]);
  }
}

// ----------------------------------------------------------------
extern "C" void kernel_launch(void* const* d_in, const int* in_sizes, int n_in,
                              void* d_out, int out_size, void* d_ws, size_t ws_size,
                              hipStream_t stream) {
  const float* x = (const float*)d_in[0];
  const float* c0 = (const float*)d_in[1];
  const float* c1 = (const float*)d_in[2];
  const float* c2 = (const float*)d_in[3];
  const float* bias = (const float*)d_in[4];
  float* out = (float*)d_out;

  const int B = 8192, F = 4096;
  char* ws = (char*)d_ws;
  float* scal = (float*)ws;                              // [0]=ssq_x [1]=ssq_xl0 [2]=ssq_xl1
  bf16* xbf = (bf16*)(ws + 256);                         // 64 MiB (x bf16; reused as xl1)
  bf16* Wt = (bf16*)(ws + 256 + (size_t)67108864);       // 32 MiB
  bf16* G = (bf16*)(ws + 256 + (size_t)100663296);       // 32 MiB
  bf16* xl0 = (bf16*)(ws + 256 + (size_t)134217728);     // 64 MiB
  bf16* xl1 = xbf;
  float* mbias = out;  // d_out doubles as fp32 mbias scratch until final GEMM

  k_init<<<1, 64, 0, stream>>>(scal);
  k_cast_ssq<<<1024, 256, 0, stream>>>(x, xbf, &scal[0], B * F / 4);
  k_buildW<<<4096, 256, 0, stream>>>(c0, c1, c2, Wt);

  dim3 gG(F / 128, F / 128);
  // G = W^T W = Wt @ Wt^T  (BT form: A=Wt, Bt=Wt)
  k_gemm<1><<<gG, 256, 0, stream>>>(Wt, Wt, F, F, F, nullptr, nullptr, nullptr,
                                    nullptr, G, nullptr, nullptr);
  dim3 g1(F / 128, B / 128);
  // mv = x @ W  (Bt = Wt) ; writes mbias(fp32->d_out), xl0(bf16), ssq_xl0
  k_gemm<0><<<g1, 256, 0, stream>>>(xbf, Wt, B, F, F, bias, nullptr, nullptr,
                                    mbias, xl0, &scal[0], &scal[1]);
  // xl1 = xl0 - xl0@G + mbias + gate(ssq_xl0)   (G symmetric -> Bt = G)
  k_gemm<2><<<g1, 256, 0, stream>>>(xl0, G, B, F, F, nullptr, xl0, mbias,
                                    nullptr, xl1, &scal[1], &scal[2]);
  // out = xl1 - xl1@G + mbias + gate(ssq_xl1)
  k_gemm<3><<<g1, 256, 0, stream>>>(xl1, G, B, F, F, nullptr, xl1, mbias,
                                    out, nullptr, &scal[2], nullptr);
}

// Round 2
// 1588.396 us; speedup vs baseline: 1.0797x; 1.0797x over previous
//
#include <hip/hip_runtime.h>
#include <stdint.h>

typedef __bf16 bf16;
typedef __bf16 bf16x4 __attribute__((ext_vector_type(4)));
typedef __bf16 bf16x8 __attribute__((ext_vector_type(8)));
typedef float f32x4 __attribute__((ext_vector_type(4)));

#define GLD_LDS16(g, l)                                                        \
  __builtin_amdgcn_global_load_lds(                                            \
      (const __attribute__((address_space(1))) void*)(g),                      \
      (__attribute__((address_space(3))) void*)(l), 16, 0, 0)

// ---------------------------------------------------------------- init: zero ssq accumulators
__global__ void k_init(float* s) {
  if (threadIdx.x < 3) s[threadIdx.x] = 0.0f;
}

// ---------------------------------------------------------------- cast x fp32 -> bf16, fused ||x||^2
__global__ void k_cast_ssq(const float* __restrict__ x, bf16* __restrict__ xb,
                           float* __restrict__ ssq, int n4) {
  int tid = blockIdx.x * blockDim.x + threadIdx.x;
  int stride = gridDim.x * blockDim.x;
  const float4* x4 = (const float4*)x;
  bf16x4* xb4 = (bf16x4*)xb;
  float acc = 0.f;
  for (int i = tid; i < n4; i += stride) {
    float4 v = x4[i];
    acc += v.x * v.x + v.y * v.y + v.z * v.z + v.w * v.w;
    bf16x4 b;
    b.x = (bf16)v.x; b.y = (bf16)v.y; b.z = (bf16)v.z; b.w = (bf16)v.w;
    xb4[i] = b;
  }
#pragma unroll
  for (int off = 32; off; off >>= 1) acc += __shfl_down(acc, off);
  __shared__ float red[4];
  if ((threadIdx.x & 63) == 0) red[threadIdx.x >> 6] = acc;
  __syncthreads();
  if (threadIdx.x == 0) atomicAdd(ssq, red[0] + red[1] + red[2] + red[3]);
}

// ---------------------------------------------------------------- build Wt (bf16, [out=4096][in=4096] row-major)
__global__ void k_buildW(const float* __restrict__ c0, const float* __restrict__ c1,
                         const float* __restrict__ c2, bf16* __restrict__ Wt) {
  int t = blockIdx.x * 256 + threadIdx.x;  // 4096 * 16 * 16 threads
  int j = t >> 8;
  int i0 = (t >> 4) & 15;
  int i1 = t & 15;
  int j0 = j >> 8, j1 = (j >> 4) & 15, j2 = j & 15;
  float t0[8];
#pragma unroll
  for (int r1 = 0; r1 < 8; ++r1) t0[r1] = c0[(i0 * 16 + j0) * 8 + r1];
  float a[8];
#pragma unroll
  for (int r2 = 0; r2 < 8; ++r2) {
    float s = 0.f;
#pragma unroll
    for (int r1 = 0; r1 < 8; ++r1) s += t0[r1] * c1[((r1 * 16 + i1) * 16 + j1) * 8 + r2];
    a[r2] = s;
  }
  union { bf16 h[16]; bf16x8 v[2]; } u;
#pragma unroll
  for (int i2 = 0; i2 < 16; ++i2) {
    float s = 0.f;
#pragma unroll
    for (int r2 = 0; r2 < 8; ++r2) s += a[r2] * c2[(r2 * 16 + i2) * 16 + j2];
    u.h[i2] = (bf16)s;
  }
  bf16* dst = Wt + (size_t)j * 4096 + i0 * 256 + i1 * 16;
  ((bf16x8*)dst)[0] = u.v[0];
  ((bf16x8*)dst)[1] = u.v[1];
}

// ---------------------------------------------------------------- BT-form GEMM: C[m,n] = sum_k A[m,k]*Bt[n,k]
// 128x128 tile, BK=32, 256 thr = 4 waves (2x2 of 64x64), mfma_f32_16x16x32_bf16 4x4/wave.
// LDS: 16B chunk c of row r stored at slot (c ^ ((r>>1)&3)) -> conflict-free ds_read_b128.
// MODE 0: xl0 = acc + bias + gate0 ; bf_out ; ssq_out
// MODE 1: G (symmetric): blocks bx<by exit; write acc and mirror
// MODE 2: xl1 = 2*xl0 - acc + (gate1-gate0) ; bf_out ; ssq_out          [A = xl0]
// MODE 3: out = xl_prev - acc + xl0 + (gate2-gate0)  (fp32)             [A = xl1]
template <int MODE>
__global__ __launch_bounds__(256) void k_gemm(
    const bf16* __restrict__ A, const bf16* __restrict__ Bt, int M, int N, int K,
    const float* __restrict__ bias, const bf16* __restrict__ xl0,
    const bf16* __restrict__ xl_prev, float* f32_out, bf16* __restrict__ bf_out,
    const float* __restrict__ ssq_a, const float* __restrict__ ssq_b,
    float* __restrict__ ssq_out) {
  const int bx = blockIdx.x, by = blockIdx.y;
  if constexpr (MODE == 1) {
    if (bx < by) return;  // G symmetric: compute upper triangle only
  }
  __shared__ char smem[16384];  // As[128][32] bf16 | Bs[128][32] bf16
  __shared__ float red[4];
  bf16* As = (bf16*)smem;
  bf16* Bs = (bf16*)(smem + 8192);

  const int t = threadIdx.x;
  const int w = t >> 6, lane = t & 63;
  const int q = lane >> 4, lr = lane & 15;
  const int wm = w & 1, wn = w >> 1;

  f32x4 acc[4][4];
#pragma unroll
  for (int i = 0; i < 4; ++i)
#pragma unroll
    for (int j = 0; j < 4; ++j) acc[i][j] = (f32x4){0.f, 0.f, 0.f, 0.f};

  // staging: thread t fills LDS slot t*16 of each 128x32 half-tile.
  // slot (row, cs) holds global chunk cl = cs ^ ((row>>1)&3); row = t>>2.
  const int rowA = t >> 2;
  const int colc = ((t & 3) ^ ((t >> 3) & 3)) * 8;
  const bf16* pA = A + (size_t)(by * 128 + rowA) * K + colc;
  const bf16* pA2 = pA + (size_t)64 * K;
  const bf16* pB = Bt + (size_t)(bx * 128 + rowA) * K + colc;
  const bf16* pB2 = pB + (size_t)64 * K;
  char* ldsA = smem + w * 1024;          // wave-uniform bases
  char* ldsA2 = smem + 4096 + w * 1024;
  char* ldsB = smem + 8192 + w * 1024;
  char* ldsB2 = smem + 12288 + w * 1024;

  const int swl = (lr >> 1) & 3;  // lane-constant swizzle for fragment reads

  for (int k0 = 0; k0 < K; k0 += 32) {
    __syncthreads();
    GLD_LDS16(pA, ldsA);
    GLD_LDS16(pA2, ldsA2);
    GLD_LDS16(pB, ldsB);
    GLD_LDS16(pB2, ldsB2);
    pA += 32; pA2 += 32; pB += 32; pB2 += 32;
    __syncthreads();  // drains vmcnt -> LDS valid
    bf16x8 af[4], bfr[4];
#pragma unroll
    for (int mi = 0; mi < 4; ++mi)
      af[mi] = *(const bf16x8*)(As + (wm * 64 + mi * 16 + lr) * 32 + (q ^ swl) * 8);
#pragma unroll
    for (int ni = 0; ni < 4; ++ni)
      bfr[ni] = *(const bf16x8*)(Bs + (wn * 64 + ni * 16 + lr) * 32 + (q ^ swl) * 8);
#pragma unroll
    for (int mi = 0; mi < 4; ++mi)
#pragma unroll
      for (int ni = 0; ni < 4; ++ni)
        acc[mi][ni] =
            __builtin_amdgcn_mfma_f32_16x16x32_bf16(af[mi], bfr[ni], acc[mi][ni], 0, 0, 0);
  }

  // epilogue. C/D layout: col = lane&15, row = (lane>>4)*4 + reg  [m89-verified]
  float gate = 0.f;
  if constexpr (MODE == 0) {
    gate = (*ssq_a > 1.0f) ? 0.f : -1.f;  // gate0
  } else if constexpr (MODE == 2 || MODE == 3) {
    float g0 = (*ssq_a > 1.0f) ? 0.f : -1.f;
    float gt = (*ssq_b > 1.0f) ? 0.f : -1.f;
    gate = gt - g0;
  }
  float ssql = 0.f;
  const int gm0 = by * 128 + wm * 64 + q * 4;
  const int gn0 = bx * 128 + wn * 64 + lr;
#pragma unroll
  for (int mi = 0; mi < 4; ++mi) {
#pragma unroll
    for (int r = 0; r < 4; ++r) {
      int row = gm0 + mi * 16 + r;
      size_t base = (size_t)row * N + gn0;
#pragma unroll
      for (int ni = 0; ni < 4; ++ni) {
        size_t idx = base + ni * 16;
        float v = acc[mi][ni][r];
        if constexpr (MODE == 0) {
          float xl = v + bias[gn0 + ni * 16] + gate;
          bf_out[idx] = (bf16)xl;
          ssql += xl * xl;
        } else if constexpr (MODE == 1) {
          bf_out[idx] = (bf16)v;
          if (bx != by) bf_out[(size_t)(gn0 + ni * 16) * N + row] = (bf16)v;
        } else if constexpr (MODE == 2) {
          float xl = 2.0f * (float)xl0[idx] - v + gate;
          bf_out[idx] = (bf16)xl;
          ssql += xl * xl;
        } else {
          f32_out[idx] = (float)xl_prev[idx] - v + (float)xl0[idx] + gate;
        }
      }
    }
  }
  if constexpr (MODE == 0 || MODE == 2) {
#pragma unroll
    for (int off = 32; off; off >>= 1) ssql += __shfl_down(ssql, off);
    if (lane == 0) red[w] = ssql;
    __syncthreads();
    if (t == 0) atomicAdd(ssq_out, red[0] + red[1] + red[2] + red[3]);
  }
}

// ----------------------------------------------------------------
extern "C" void kernel_launch(void* const* d_in, const int* in_sizes, int n_in,
                              void* d_out, int out_size, void* d_ws, size_t ws_size,
                              hipStream_t stream) {
  const float* x = (const float*)d_in[0];
  const float* c0 = (const float*)d_in[1];
  const float* c1 = (const float*)d_in[2];
  const float* c2 = (const float*)d_in[3];
  const float* bias = (const float*)d_in[4];
  float* out = (float*)d_out;

  const int B = 8192, F = 4096;
  char* ws = (char*)d_ws;
  float* scal = (float*)ws;                              // [0]=ssq_x [1]=ssq_xl0 [2]=ssq_xl1
  bf16* xbf = (bf16*)(ws + 256);                         // 64 MiB (x bf16; reused as xl1)
  bf16* Wt = (bf16*)(ws + 256 + (size_t)67108864);       // 32 MiB
  bf16* G = (bf16*)(ws + 256 + (size_t)100663296);       // 32 MiB
  bf16* xl0 = (bf16*)(ws + 256 + (size_t)134217728);     // 64 MiB
  bf16* xl1 = xbf;  // xbf dead after mv GEMM

  k_init<<<1, 64, 0, stream>>>(scal);
  k_cast_ssq<<<1024, 256, 0, stream>>>(x, xbf, &scal[0], B * F / 4);
  k_buildW<<<4096, 256, 0, stream>>>(c0, c1, c2, Wt);

  dim3 gG(F / 128, F / 128);
  // G = W^T W = Wt @ Wt^T  (BT form: A=Wt, Bt=Wt), symmetric -> triangle + mirror
  k_gemm<1><<<gG, 256, 0, stream>>>(Wt, Wt, F, F, F, nullptr, nullptr, nullptr,
                                    nullptr, G, nullptr, nullptr, nullptr);
  dim3 g1(F / 128, B / 128);
  // xl0 = x@W + bias + gate0
  k_gemm<0><<<g1, 256, 0, stream>>>(xbf, Wt, B, F, F, bias, nullptr, nullptr,
                                    nullptr, xl0, &scal[0], nullptr, &scal[1]);
  // xl1 = 2*xl0 - xl0@G + (gate1-gate0)
  k_gemm<2><<<g1, 256, 0, stream>>>(xl0, G, B, F, F, nullptr, xl0, nullptr,
                                    nullptr, xl1, &scal[0], &scal[1], &scal[2]);
  // out = xl1 - xl1@G + xl0 + (gate2-gate0)
  k_gemm<3><<<g1, 256, 0, stream>>>(xl1, G, B, F, F, nullptr, xl0, xl1,
                                    out, nullptr, &scal[0], &scal[2], nullptr);
}

// Round 3
// 1370.785 us; speedup vs baseline: 1.2511x; 1.1587x over previous
//
#include <hip/hip_runtime.h>
#include <stdint.h>

typedef __bf16 bf16;
typedef __bf16 bf16x4 __attribute__((ext_vector_type(4)));
typedef __bf16 bf16x8 __attribute__((ext_vector_type(8)));
typedef float f32x4 __attribute__((ext_vector_type(4)));

#define GLD_LDS16(g, l)                                                        \
  __builtin_amdgcn_global_load_lds(                                            \
      (const __attribute__((address_space(1))) void*)(g),                      \
      (__attribute__((address_space(3))) void*)(l), 16, 0, 0)

#define BAR() asm volatile("s_barrier" ::: "memory")
#define WAIT4() asm volatile("s_waitcnt vmcnt(4)" ::: "memory")
#define WAIT0() asm volatile("s_waitcnt vmcnt(0)" ::: "memory")

// ---------------------------------------------------------------- init: zero ssq accumulators
__global__ void k_init(float* s) {
  if (threadIdx.x < 3) s[threadIdx.x] = 0.0f;
}

// ---------------------------------------------------------------- cast x fp32 -> bf16, fused ||x||^2
__global__ void k_cast_ssq(const float* __restrict__ x, bf16* __restrict__ xb,
                           float* __restrict__ ssq, int n4) {
  int tid = blockIdx.x * blockDim.x + threadIdx.x;
  int stride = gridDim.x * blockDim.x;
  const float4* x4 = (const float4*)x;
  bf16x4* xb4 = (bf16x4*)xb;
  float acc = 0.f;
  for (int i = tid; i < n4; i += stride) {
    float4 v = x4[i];
    acc += v.x * v.x + v.y * v.y + v.z * v.z + v.w * v.w;
    bf16x4 b;
    b.x = (bf16)v.x; b.y = (bf16)v.y; b.z = (bf16)v.z; b.w = (bf16)v.w;
    xb4[i] = b;
  }
#pragma unroll
  for (int off = 32; off; off >>= 1) acc += __shfl_down(acc, off);
  __shared__ float red[4];
  if ((threadIdx.x & 63) == 0) red[threadIdx.x >> 6] = acc;
  __syncthreads();
  if (threadIdx.x == 0) atomicAdd(ssq, red[0] + red[1] + red[2] + red[3]);
}

// ---------------------------------------------------------------- build Wt (bf16, [out=4096][in=4096] row-major)
__global__ void k_buildW(const float* __restrict__ c0, const float* __restrict__ c1,
                         const float* __restrict__ c2, bf16* __restrict__ Wt) {
  int t = blockIdx.x * 256 + threadIdx.x;  // 4096 * 16 * 16 threads
  int j = t >> 8;
  int i0 = (t >> 4) & 15;
  int i1 = t & 15;
  int j0 = j >> 8, j1 = (j >> 4) & 15, j2 = j & 15;
  float t0[8];
#pragma unroll
  for (int r1 = 0; r1 < 8; ++r1) t0[r1] = c0[(i0 * 16 + j0) * 8 + r1];
  float a[8];
#pragma unroll
  for (int r2 = 0; r2 < 8; ++r2) {
    float s = 0.f;
#pragma unroll
    for (int r1 = 0; r1 < 8; ++r1) s += t0[r1] * c1[((r1 * 16 + i1) * 16 + j1) * 8 + r2];
    a[r2] = s;
  }
  union { bf16 h[16]; bf16x8 v[2]; } u;
#pragma unroll
  for (int i2 = 0; i2 < 16; ++i2) {
    float s = 0.f;
#pragma unroll
    for (int r2 = 0; r2 < 8; ++r2) s += a[r2] * c2[(r2 * 16 + i2) * 16 + j2];
    u.h[i2] = (bf16)s;
  }
  bf16* dst = Wt + (size_t)j * 4096 + i0 * 256 + i1 * 16;
  ((bf16x8*)dst)[0] = u.v[0];
  ((bf16x8*)dst)[1] = u.v[1];
}

// ---------------------------------------------------------------- BT-form GEMM: C[m,n] = sum_k A[m,k]*Bt[n,k]
// 128x128 tile, BK=32, 256 thr = 4 waves (2x2 of 64x64), mfma_f32_16x16x32_bf16 4x4/wave.
// Double-buffered LDS (2x16KB), AITER-style pipeline: raw s_barrier (no drain),
// manual s_waitcnt vmcnt(4) so the just-issued prefetch stays in flight across the barrier.
// LDS: 16B chunk c of row r stored at slot (c ^ ((r>>1)&3)) -> conflict-free ds_read_b128.
// MODE 0: xl0 = acc + bias + gate0 ; bf_out ; ssq_out
// MODE 1: G (symmetric): blocks bx<by exit; write acc and mirror
// MODE 2: xl1 = 2*xl0 - acc + (gate1-gate0) ; bf_out ; ssq_out          [A = xl0]
// MODE 3: out = xl_prev - acc + xl0 + (gate2-gate0)  (fp32)             [A = xl1]
template <int MODE>
__global__ __launch_bounds__(256) void k_gemm(
    const bf16* __restrict__ A, const bf16* __restrict__ Bt, int M, int N, int K,
    const float* __restrict__ bias, const bf16* __restrict__ xl0,
    const bf16* __restrict__ xl_prev, float* f32_out, bf16* __restrict__ bf_out,
    const float* __restrict__ ssq_a, const float* __restrict__ ssq_b,
    float* __restrict__ ssq_out) {
  const int bx = blockIdx.x, by = blockIdx.y;
  if constexpr (MODE == 1) {
    if (bx < by) return;  // G symmetric: compute upper triangle only
  }
  __shared__ char smem[32768];  // 2 x (As[128][32] | Bs[128][32]) bf16

  const int t = threadIdx.x;
  const int w = t >> 6, lane = t & 63;
  const int q = lane >> 4, lr = lane & 15;
  const int wm = w & 1, wn = w >> 1;

  // gate: hoisted ABOVE the K-loop so its load retires before our manual vmcnt counting
  float gate = 0.f;
  if constexpr (MODE == 0) {
    gate = (*ssq_a > 1.0f) ? 0.f : -1.f;  // gate0
  } else if constexpr (MODE == 2 || MODE == 3) {
    float g0 = (*ssq_a > 1.0f) ? 0.f : -1.f;
    float gt = (*ssq_b > 1.0f) ? 0.f : -1.f;
    gate = gt - g0;
  }

  f32x4 acc[4][4];
#pragma unroll
  for (int i = 0; i < 4; ++i)
#pragma unroll
    for (int j = 0; j < 4; ++j) acc[i][j] = (f32x4){0.f, 0.f, 0.f, 0.f};

  // staging: thread t fills LDS slot t*16 of each 128x32 half-tile.
  // slot (row, cs) holds global chunk cl = cs ^ ((row>>1)&3); row = t>>2.
  const int rowA = t >> 2;
  const int colc = ((t & 3) ^ ((t >> 3) & 3)) * 8;
  const bf16* pA = A + (size_t)(by * 128 + rowA) * K + colc;
  const bf16* pA2 = pA + (size_t)64 * K;
  const bf16* pB = Bt + (size_t)(bx * 128 + rowA) * K + colc;
  const bf16* pB2 = pB + (size_t)64 * K;

  const int swl = (lr >> 1) & 3;  // lane-constant swizzle for fragment reads

#define GLD4(buf)                                                              \
  do {                                                                         \
    GLD_LDS16(pA, smem + (buf)*16384 + w * 1024);                              \
    GLD_LDS16(pA2, smem + (buf)*16384 + 4096 + w * 1024);                      \
    GLD_LDS16(pB, smem + (buf)*16384 + 8192 + w * 1024);                       \
    GLD_LDS16(pB2, smem + (buf)*16384 + 12288 + w * 1024);                     \
    pA += 32; pA2 += 32; pB += 32; pB2 += 32;                                  \
  } while (0)

#define COMPUTE(buf)                                                           \
  do {                                                                         \
    const bf16* As_ = (const bf16*)(smem + (buf)*16384);                       \
    const bf16* Bs_ = (const bf16*)(smem + (buf)*16384 + 8192);                \
    bf16x8 af[4], bfr[4];                                                      \
    _Pragma("unroll") for (int mi = 0; mi < 4; ++mi)                           \
        af[mi] = *(const bf16x8*)(As_ + (wm * 64 + mi * 16 + lr) * 32 +        \
                                  (q ^ swl) * 8);                              \
    _Pragma("unroll") for (int ni = 0; ni < 4; ++ni)                           \
        bfr[ni] = *(const bf16x8*)(Bs_ + (wn * 64 + ni * 16 + lr) * 32 +       \
                                   (q ^ swl) * 8);                             \
    _Pragma("unroll") for (int mi = 0; mi < 4; ++mi)                           \
        _Pragma("unroll") for (int ni = 0; ni < 4; ++ni)                       \
            acc[mi][ni] = __builtin_amdgcn_mfma_f32_16x16x32_bf16(             \
                af[mi], bfr[ni], acc[mi][ni], 0, 0, 0);                        \
  } while (0)

  // K = 4096 -> 128 tiles of BK=32. Prologue loads tile 0; steady state keeps
  // one tile in flight across each barrier (vmcnt(4): 4 newest loads pending).
  GLD4(0);
#pragma unroll 1
  for (int it = 0; it < 63; ++it) {
    BAR();            // all waves done ds_reading buf1 (prev pair) -> safe to overwrite
    GLD4(1);          // prefetch tile 2it+1
    WAIT4();          // oldest 4 (tile 2it, buf0) landed; prefetch stays in flight
    BAR();
    COMPUTE(0);       // tile 2it
    BAR();
    GLD4(0);          // prefetch tile 2it+2
    WAIT4();
    BAR();
    COMPUTE(1);       // tile 2it+1
  }
  BAR();
  GLD4(1);            // tile 127
  WAIT4();
  BAR();
  COMPUTE(0);         // tile 126
  BAR();
  WAIT0();
  BAR();
  COMPUTE(1);         // tile 127

  // epilogue. C/D layout: col = lane&15, row = (lane>>4)*4 + reg  [m89-verified]
  float* red = (float*)smem;  // buf0 region, dead (final compute used buf1)
  float ssql = 0.f;
  const int gm0 = by * 128 + wm * 64 + q * 4;
  const int gn0 = bx * 128 + wn * 64 + lr;
#pragma unroll
  for (int mi = 0; mi < 4; ++mi) {
#pragma unroll
    for (int r = 0; r < 4; ++r) {
      int row = gm0 + mi * 16 + r;
      size_t base = (size_t)row * N + gn0;
#pragma unroll
      for (int ni = 0; ni < 4; ++ni) {
        size_t idx = base + ni * 16;
        float v = acc[mi][ni][r];
        if constexpr (MODE == 0) {
          float xl = v + bias[gn0 + ni * 16] + gate;
          bf_out[idx] = (bf16)xl;
          ssql += xl * xl;
        } else if constexpr (MODE == 1) {
          bf_out[idx] = (bf16)v;
          if (bx != by) bf_out[(size_t)(gn0 + ni * 16) * N + row] = (bf16)v;
        } else if constexpr (MODE == 2) {
          float xl = 2.0f * (float)xl0[idx] - v + gate;
          bf_out[idx] = (bf16)xl;
          ssql += xl * xl;
        } else {
          f32_out[idx] = (float)xl_prev[idx] - v + (float)xl0[idx] + gate;
        }
      }
    }
  }
  if constexpr (MODE == 0 || MODE == 2) {
#pragma unroll
    for (int off = 32; off; off >>= 1) ssql += __shfl_down(ssql, off);
    __syncthreads();  // final-compute ds_reads all consumed; reuse smem for reduce
    if (lane == 0) red[w] = ssql;
    __syncthreads();
    if (t == 0) atomicAdd(ssq_out, red[0] + red[1] + red[2] + red[3]);
  }
#undef GLD4
#undef COMPUTE
}

// ----------------------------------------------------------------
extern "C" void kernel_launch(void* const* d_in, const int* in_sizes, int n_in,
                              void* d_out, int out_size, void* d_ws, size_t ws_size,
                              hipStream_t stream) {
  const float* x = (const float*)d_in[0];
  const float* c0 = (const float*)d_in[1];
  const float* c1 = (const float*)d_in[2];
  const float* c2 = (const float*)d_in[3];
  const float* bias = (const float*)d_in[4];
  float* out = (float*)d_out;

  const int B = 8192, F = 4096;
  char* ws = (char*)d_ws;
  float* scal = (float*)ws;                              // [0]=ssq_x [1]=ssq_xl0 [2]=ssq_xl1
  bf16* xbf = (bf16*)(ws + 256);                         // 64 MiB (x bf16; reused as xl1)
  bf16* Wt = (bf16*)(ws + 256 + (size_t)67108864);       // 32 MiB
  bf16* G = (bf16*)(ws + 256 + (size_t)100663296);       // 32 MiB
  bf16* xl0 = (bf16*)(ws + 256 + (size_t)134217728);     // 64 MiB
  bf16* xl1 = xbf;  // xbf dead after mv GEMM

  k_init<<<1, 64, 0, stream>>>(scal);
  k_cast_ssq<<<1024, 256, 0, stream>>>(x, xbf, &scal[0], B * F / 4);
  k_buildW<<<4096, 256, 0, stream>>>(c0, c1, c2, Wt);

  dim3 gG(F / 128, F / 128);
  // G = W^T W = Wt @ Wt^T  (BT form: A=Wt, Bt=Wt), symmetric -> triangle + mirror
  k_gemm<1><<<gG, 256, 0, stream>>>(Wt, Wt, F, F, F, nullptr, nullptr, nullptr,
                                    nullptr, G, nullptr, nullptr, nullptr);
  dim3 g1(F / 128, B / 128);
  // xl0 = x@W + bias + gate0
  k_gemm<0><<<g1, 256, 0, stream>>>(xbf, Wt, B, F, F, bias, nullptr, nullptr,
                                    nullptr, xl0, &scal[0], nullptr, &scal[1]);
  // xl1 = 2*xl0 - xl0@G + (gate1-gate0)
  k_gemm<2><<<g1, 256, 0, stream>>>(xl0, G, B, F, F, nullptr, xl0, nullptr,
                                    nullptr, xl1, &scal[0], &scal[1], &scal[2]);
  // out = xl1 - xl1@G + xl0 + (gate2-gate0)
  k_gemm<3><<<g1, 256, 0, stream>>>(xl1, G, B, F, F, nullptr, xl0, xl1,
                                    out, nullptr, &scal[0], &scal[2], nullptr);
}